// Round 1
// baseline (454.613 us; speedup 1.0000x reference)
//
#include <hip/hip_runtime.h>
#include <math.h>

// QCQP via FISTA. One 1024-thread workgroup per batch (was 512).
// Rationale (rocprof): Occupancy 23% = 2 waves/SIMD, latency-bound
// (VALUBusy 44%, MfmaUtil 6.7%, HBM 3.4%). Per-thread state halved
// (h[64], acc[8][2] = 64 regs) so total regs <= 128/thread ->
// 16 waves/CU = 4 waves/SIMD.
// Wave (ws = w&7, rh = w>>3) owns H rows 128rh..128rh+127 x cols
// 32ws..32ws+31; lane l holds rows 128rh+2l, +2l+1 (h[2][32]).
// The y-update for cols 32ws.. is computed redundantly by both rh
// waves of a slice -> ybuf stays wave-private -> still exactly ONE
// __syncthreads per iteration with ping-pong red buffers (verified
// scheme from the 512-thread kernel).
// GEMM H = P^T P on matrix cores via bf16 split precision, identical
// arithmetic to the previous kernel; fragments are staged once per
// 32-k chunk and shared by all 16 waves. frag arrays are union'd with
// Hbuf (remap scratch) - disjoint phases separated by the chunk loop's
// trailing barrier.

namespace {

constexpr int NDIM = 256;
constexpr int NCON = 128;
constexpr int PITERS = 20;
constexpr int FITERS = 100;

typedef short bf16x8 __attribute__((ext_vector_type(8)));
typedef float f32x4  __attribute__((ext_vector_type(4)));

struct Smem {
    union {
        struct {                                 // GEMM phase
            unsigned short fragHi[16 * 64 * 8];  // 16 KB
            unsigned short fragLo[16 * 64 * 8];  // 16 KB
        };
        float Hbuf[16][32 * 36];                 // 73.7 KB, remap phase only
    };
    float red[2][16][128];                       // 16 KB matvec partials, ping-pong
    float ybuf[16][32];                          // per-wave y/v slice
    float scal[16];
};                                               // total ~92.2 KB < 160 KB

__device__ __forceinline__ unsigned short bf16rne(float x) {
    unsigned u = __float_as_uint(x);
    unsigned r = u + 0x7FFFu + ((u >> 16) & 1u);
    return (unsigned short)(r >> 16);
}

// partial (H x) for this thread's 2 rows over its wave's 32 cols.
__device__ __forceinline__ void mv(const float (&h)[64],
                                   const float* __restrict__ xsrc,
                                   float* __restrict__ redw, int l)
{
    float pw0 = 0.f, pw1 = 0.f;
#pragma unroll
    for (int jj = 0; jj < 8; ++jj) {
        float4 x4 = *(const float4*)(xsrc + jj * 4);   // wave-uniform broadcast
        pw0 = fmaf(h[0 * 32 + jj * 4 + 0], x4.x, pw0);
        pw0 = fmaf(h[0 * 32 + jj * 4 + 1], x4.y, pw0);
        pw0 = fmaf(h[0 * 32 + jj * 4 + 2], x4.z, pw0);
        pw0 = fmaf(h[0 * 32 + jj * 4 + 3], x4.w, pw0);
        pw1 = fmaf(h[1 * 32 + jj * 4 + 0], x4.x, pw1);
        pw1 = fmaf(h[1 * 32 + jj * 4 + 1], x4.y, pw1);
        pw1 = fmaf(h[1 * 32 + jj * 4 + 2], x4.z, pw1);
        pw1 = fmaf(h[1 * 32 + jj * 4 + 3], x4.w, pw1);
    }
    *(float2*)(redw + 2 * l) = make_float2(pw0, pw1);
}

// sum the 8 col-slice partials for rows (base, base+1) of one row-half.
__device__ __forceinline__ float2 gather_pair(const float (*red8)[128], int base)
{
    float s0 = 0.f, s1 = 0.f;
#pragma unroll
    for (int c2 = 0; c2 < 8; ++c2) {
        float2 p = *(const float2*)&red8[c2][base];
        s0 += p.x; s1 += p.y;
    }
    return make_float2(s0, s1);
}

__global__ __launch_bounds__(1024)
void qcqp_fista(const float* __restrict__ P, const float* __restrict__ q,
                const float* __restrict__ ln_, const float* __restrict__ mu,
                float* __restrict__ out)
{
    __shared__ Smem sm;
    const int b = blockIdx.x;
    const int t = threadIdx.x;
    const int w  = t >> 6;        // wave 0..15
    const int l  = t & 63;
    const int ws = w & 7;         // col slice: cols 32ws..32ws+31
    const int rh = w >> 3;        // row half: rows 128rh..128rh+127

    const float* Pb = P + (size_t)b * (NDIM * NDIM);

    // ================== H = P^T P via bf16-split MFMA ==================
    // Staging roles: thread -> (col, k-quad). 1024 threads cover all
    // 256 cols x 4 quads of a 32-k chunk directly.
    const int col  = t & 255;
    const int qd   = t >> 8;      // 0..3
    const int tile = col >> 4;

    float pf[8];
    auto load_chunk = [&](int cc) {
        const float* src = Pb + (cc * 32 + qd * 8) * 256 + col;
#pragma unroll
        for (int j = 0; j < 8; ++j) pf[j] = src[j * 256];   // coalesced
    };

    f32x4 acc[8][2];
#pragma unroll
    for (int i = 0; i < 8; ++i)
#pragma unroll
        for (int j = 0; j < 2; ++j)
#pragma unroll
            for (int e = 0; e < 4; ++e) acc[i][j][e] = 0.0f;

    load_chunk(0);
    for (int c = 0; c < 8; ++c) {
        // convert pf -> hi/lo bf16, one 16B store per precision
        unsigned hw[4], lw[4];
#pragma unroll
        for (int jp = 0; jp < 4; ++jp) {
            float f0 = pf[2 * jp], f1 = pf[2 * jp + 1];
            unsigned short h0 = bf16rne(f0), h1 = bf16rne(f1);
            float r0 = f0 - __uint_as_float((unsigned)h0 << 16);
            float r1 = f1 - __uint_as_float((unsigned)h1 << 16);
            unsigned short lo0 = bf16rne(r0), lo1 = bf16rne(r1);
            hw[jp] = (unsigned)h0 | ((unsigned)h1 << 16);
            lw[jp] = (unsigned)lo0 | ((unsigned)lo1 << 16);
        }
        const int slot = tile * 64 + (col & 15) + 16 * qd;
        ((uint4*)sm.fragHi)[slot] = make_uint4(hw[0], hw[1], hw[2], hw[3]);
        ((uint4*)sm.fragLo)[slot] = make_uint4(lw[0], lw[1], lw[2], lw[3]);
        __syncthreads();
        if (c < 7) load_chunk(c + 1);          // prefetch during MFMAs

        const bf16x8* FH = (const bf16x8*)sm.fragHi;
        const bf16x8* FL = (const bf16x8*)sm.fragLo;
        bf16x8 bh0 = FH[(2 * ws) * 64 + l];
        bf16x8 bl0 = FL[(2 * ws) * 64 + l];
        bf16x8 bh1 = FH[(2 * ws + 1) * 64 + l];
        bf16x8 bl1 = FL[(2 * ws + 1) * 64 + l];
#pragma unroll
        for (int tt = 0; tt < 8; ++tt) {
            bf16x8 ah = FH[(8 * rh + tt) * 64 + l];
            bf16x8 al = FL[(8 * rh + tt) * 64 + l];
            acc[tt][0] = __builtin_amdgcn_mfma_f32_16x16x32_bf16(ah, bh0, acc[tt][0], 0, 0, 0);
            acc[tt][0] = __builtin_amdgcn_mfma_f32_16x16x32_bf16(al, bh0, acc[tt][0], 0, 0, 0);
            acc[tt][0] = __builtin_amdgcn_mfma_f32_16x16x32_bf16(ah, bl0, acc[tt][0], 0, 0, 0);
            acc[tt][1] = __builtin_amdgcn_mfma_f32_16x16x32_bf16(ah, bh1, acc[tt][1], 0, 0, 0);
            acc[tt][1] = __builtin_amdgcn_mfma_f32_16x16x32_bf16(al, bh1, acc[tt][1], 0, 0, 0);
            acc[tt][1] = __builtin_amdgcn_mfma_f32_16x16x32_bf16(ah, bl1, acc[tt][1], 0, 0, 0);
        }
        __syncthreads();   // MFMA frag reads done before next writes / Hbuf
    }

    // ---- acc (C layout: row=16*ta+4*(l>>4)+reg, col=16*tb+(l&15)) ->
    //      h[i*32+j] = H[128rh+2l+i][32ws+j], via per-wave LDS slice.
    //      Intra-wave only: same-wave LDS ops are ordered, no barrier. ----
    const int qd4 = (l >> 4) * 4;
    const int c16 = l & 15;
    float* Hw = sm.Hbuf[w];
    float h[64];
#pragma unroll
    for (int rc = 0; rc < 4; ++rc) {           // local rows 32rc..32rc+31
#pragma unroll
        for (int s = 0; s < 2; ++s)
#pragma unroll
            for (int tc = 0; tc < 2; ++tc)
#pragma unroll
                for (int reg = 0; reg < 4; ++reg)
                    Hw[(16 * s + qd4 + reg) * 36 + 16 * tc + c16] =
                        acc[2 * rc + s][tc][reg];
        if ((l >> 4) == rc) {                   // lanes 16rc..16rc+15
            const int lr = 2 * (l & 15);
#pragma unroll
            for (int i = 0; i < 2; ++i)
#pragma unroll
                for (int jj = 0; jj < 8; ++jj) {
                    float4 v = *(const float4*)&Hw[(lr + i) * 36 + 4 * jj];
                    h[i * 32 + jj * 4 + 0] = v.x;
                    h[i * 32 + jj * 4 + 1] = v.y;
                    h[i * 32 + jj * 4 + 2] = v.z;
                    h[i * 32 + jj * 4 + 3] = v.w;
                }
        }
    }

    // Gather geometry: rows 32ws+2l live in half rhp = ws>>2 at
    // slice-local index 32*(ws&3) + 2l; sum red slices [8*rhp + 0..7].
    const int rhp   = ws >> 2;
    const int rbase = 32 * (ws & 3);

    // ================== power iteration ==================
    if (l < 32) sm.ybuf[w][l] = 1.0f;
    int phase = 0;
    for (int it = 0; it < PITERS; ++it, ++phase) {
        mv(h, sm.ybuf[w], sm.red[phase & 1][w], l);
        __syncthreads();
        if (l < 16) {
            float2 s = gather_pair(&sm.red[phase & 1][8 * rhp], rbase + 2 * l);
            *(float2*)&sm.ybuf[w][2 * l] =
                make_float2(s.x * 0.0009765625f, s.y * 0.0009765625f);
        }
    }

    // ---- Rayleigh quotient -> step ----
    mv(h, sm.ybuf[w], sm.red[phase & 1][w], l);
    __syncthreads();
    float n1 = 0.f, n2 = 0.f;
    if (l < 16) {
        float2 hv = gather_pair(&sm.red[phase & 1][8 * rhp], rbase + 2 * l);
        float v0 = sm.ybuf[w][2 * l + 0];
        float v1 = sm.ybuf[w][2 * l + 1];
        n1 = v0 * hv.x + v1 * hv.y;
        n2 = v0 * v0 + v1 * v1;
    }
#pragma unroll
    for (int off = 1; off < 64; off <<= 1) {
        n1 += __shfl_xor(n1, off);
        n2 += __shfl_xor(n2, off);
    }
    if (l == 0 && rh == 0) { sm.scal[ws] = n1; sm.scal[8 + ws] = n2; }
    __syncthreads();
    float num = 0.f, den = 0.f;
#pragma unroll
    for (int ww = 0; ww < 8; ++ww) { num += sm.scal[ww]; den += sm.scal[8 + ww]; }
    float L = num / den;
    const float step = 1.0f / (1.05f * fmaxf(L, 1e-12f));
    ++phase;

    // ================== FISTA ==================
    float b0 = 0.f, b1 = 0.f, rr = 0.f;
    if (l < 16) {
        float2 q2 = *(const float2*)(q + b * NDIM + 32 * ws + 2 * l);
        b0 = q2.x; b1 = q2.y;
        rr = mu[b * NCON + 16 * ws + l] * ln_[b * NCON + 16 * ws + l];
    }
    float li0 = 0.f, li1 = 0.f, tcur = 1.0f;
    if (l < 32) sm.ybuf[w][l] = 0.0f;

    for (int it = 0; it < FITERS; ++it, ++phase) {
        mv(h, sm.ybuf[w], sm.red[phase & 1][w], l);
        __syncthreads();
        float tn = 0.5f * (1.0f + sqrtf(1.0f + 4.0f * tcur * tcur));
        float ratio = (tcur - 1.0f) / tn;
        tcur = tn;
        if (l < 16) {
            float2 hy = gather_pair(&sm.red[phase & 1][8 * rhp], rbase + 2 * l);
            float y0 = sm.ybuf[w][2 * l + 0];
            float y1 = sm.ybuf[w][2 * l + 1];
            float z0 = y0 - step * (hy.x + b0);
            float z1 = y1 - step * (hy.y + b1);
            float nrm = sqrtf(z0 * z0 + z1 * z1);
            float scl = (nrm > rr) ? (rr / fmaxf(nrm, 1e-30f)) : 1.0f;
            float l0 = z0 * scl, l1 = z1 * scl;
            float yn0 = l0 + ratio * (l0 - li0);
            float yn1 = l1 + ratio * (l1 - li1);
            li0 = l0; li1 = l1;
            *(float2*)&sm.ybuf[w][2 * l] = make_float2(yn0, yn1);
        }
    }

    if (rh == 0 && l < 16)
        *(float2*)(out + b * NDIM + 32 * ws + 2 * l) = make_float2(li0, li1);
}

} // namespace

extern "C" void kernel_launch(void* const* d_in, const int* in_sizes, int n_in,
                              void* d_out, int out_size, void* d_ws, size_t ws_size,
                              hipStream_t stream) {
    const float* P   = (const float*)d_in[0];
    const float* q   = (const float*)d_in[1];
    const float* l_n = (const float*)d_in[2];
    const float* mu  = (const float*)d_in[3];
    float* out = (float*)d_out;
    qcqp_fista<<<dim3(512), dim3(1024), 0, stream>>>(P, q, l_n, mu, out);
}

// Round 2
// 426.813 us; speedup vs baseline: 1.0651x; 1.0651x over previous
//
#include <hip/hip_runtime.h>
#include <math.h>

// QCQP via FISTA. One 512-thread workgroup per batch (R0 geometry).
// R1 post-mortem: iteration phase was LDS-instruction-throughput-bound
// (~2900 cy/iter of ds_read_b128 broadcasts at 16 waves). Fix: x is
// distributed via v_readlane (VALU pipe) instead of LDS broadcast reads;
// ybuf removed entirely. Inner mv is pure v_fmac with wave-uniform x.
// Cross-wave reduction keeps the verified 1-barrier/iter ping-pong red
// scheme. GEMM H = P^T P on matrix cores via bf16 split precision,
// bit-identical to the verified R0 kernel; frag arrays union'd with Hbuf
// (disjoint phases separated by the chunk loop's trailing barrier).

namespace {

constexpr int NDIM = 256;
constexpr int NCON = 128;
constexpr int PITERS = 20;
constexpr int FITERS = 100;

typedef short bf16x8 __attribute__((ext_vector_type(8)));
typedef float f32x4  __attribute__((ext_vector_type(4)));

struct Smem {
    union {
        struct {                                 // GEMM phase only
            unsigned short fragHi[16 * 64 * 8];  // 16 KB
            unsigned short fragLo[16 * 64 * 8];  // 16 KB
        };
        float Hbuf[8][32 * 36];                  // 36.9 KB, remap phase only
    };
    float red[2][8][256];                        // 16 KB matvec partials, ping-pong
    float scal[16];
};                                               // ~52 KB

__device__ __forceinline__ unsigned short bf16rne(float x) {
    unsigned u = __float_as_uint(x);
    unsigned r = u + 0x7FFFu + ((u >> 16) & 1u);
    return (unsigned short)(r >> 16);
}

__device__ __forceinline__ float readlane_f(float v, int lane) {
    return __int_as_float(__builtin_amdgcn_readlane(__float_as_int(v), lane));
}

// pw = (partial H x)_{4l..4l+3} over this wave's 32 cols; x is wave-uniform
// (readlane-broadcast, lives in SGPRs) -> zero LDS reads here.
__device__ __forceinline__ void mv_reg(const float (&h)[128], const float (&xs)[32],
                                       float* __restrict__ redw, int l)
{
    float pw0 = 0.f, pw1 = 0.f, pw2 = 0.f, pw3 = 0.f;
#pragma unroll
    for (int j = 0; j < 32; ++j) {
        pw0 = fmaf(h[0 * 32 + j], xs[j], pw0);
        pw1 = fmaf(h[1 * 32 + j], xs[j], pw1);
        pw2 = fmaf(h[2 * 32 + j], xs[j], pw2);
        pw3 = fmaf(h[3 * 32 + j], xs[j], pw3);
    }
    *(float4*)(redw + 4 * l) = make_float4(pw0, pw1, pw2, pw3);
}

// sum the 8 col-slice partials for rows (32w+2l, 32w+2l+1).
__device__ __forceinline__ float2 gather_pair(const float (*red8)[256], int w, int l)
{
    float s0 = 0.f, s1 = 0.f;
#pragma unroll
    for (int c2 = 0; c2 < 8; ++c2) {
        float2 p = *(const float2*)&red8[c2][32 * w + 2 * l];
        s0 += p.x; s1 += p.y;
    }
    return make_float2(s0, s1);
}

__global__ __launch_bounds__(512, 2)
void qcqp_fista(const float* __restrict__ P, const float* __restrict__ q,
                const float* __restrict__ ln_, const float* __restrict__ mu,
                float* __restrict__ out)
{
    __shared__ Smem sm;
    const int b = blockIdx.x;
    const int t = threadIdx.x;
    const int w = t >> 6;        // wave id = col block (cols 32w..32w+31)
    const int l = t & 63;

    const float* Pb = P + (size_t)b * (NDIM * NDIM);

    // ================== H = P^T P via bf16-split MFMA ==================
    const int col  = t & 255;
    const int half = t >> 8;
    const int tile = col >> 4;

    float pf[16];
    auto load_chunk = [&](int cc) {
#pragma unroll
        for (int g = 0; g < 2; ++g) {
            const int qd = 2 * half + g;
            const float* src = Pb + (cc * 32 + qd * 8) * 256 + col;
#pragma unroll
            for (int j = 0; j < 8; ++j) pf[g * 8 + j] = src[j * 256];
        }
    };

    f32x4 acc[16][2];
#pragma unroll
    for (int i = 0; i < 16; ++i)
#pragma unroll
        for (int j = 0; j < 2; ++j)
#pragma unroll
            for (int e = 0; e < 4; ++e) acc[i][j][e] = 0.0f;

    load_chunk(0);
    for (int c = 0; c < 8; ++c) {
#pragma unroll
        for (int g = 0; g < 2; ++g) {
            const int qd = 2 * half + g;
            unsigned hw[4], lw[4];
#pragma unroll
            for (int jp = 0; jp < 4; ++jp) {
                float f0 = pf[g * 8 + 2 * jp], f1 = pf[g * 8 + 2 * jp + 1];
                unsigned short h0 = bf16rne(f0), h1 = bf16rne(f1);
                float r0 = f0 - __uint_as_float((unsigned)h0 << 16);
                float r1 = f1 - __uint_as_float((unsigned)h1 << 16);
                unsigned short lo0 = bf16rne(r0), lo1 = bf16rne(r1);
                hw[jp] = (unsigned)h0 | ((unsigned)h1 << 16);
                lw[jp] = (unsigned)lo0 | ((unsigned)lo1 << 16);
            }
            const int slot = tile * 64 + ((col & 15) + 16 * qd);
            ((uint4*)sm.fragHi)[slot] = make_uint4(hw[0], hw[1], hw[2], hw[3]);
            ((uint4*)sm.fragLo)[slot] = make_uint4(lw[0], lw[1], lw[2], lw[3]);
        }
        __syncthreads();
        if (c < 7) load_chunk(c + 1);          // prefetch during MFMAs

        const bf16x8* FH = (const bf16x8*)sm.fragHi;
        const bf16x8* FL = (const bf16x8*)sm.fragLo;
        bf16x8 bh0 = FH[(2 * w) * 64 + l];
        bf16x8 bl0 = FL[(2 * w) * 64 + l];
        bf16x8 bh1 = FH[(2 * w + 1) * 64 + l];
        bf16x8 bl1 = FL[(2 * w + 1) * 64 + l];
#pragma unroll
        for (int tr = 0; tr < 16; ++tr) {
            bf16x8 ah = FH[tr * 64 + l];
            bf16x8 al = FL[tr * 64 + l];
            acc[tr][0] = __builtin_amdgcn_mfma_f32_16x16x32_bf16(ah, bh0, acc[tr][0], 0, 0, 0);
            acc[tr][0] = __builtin_amdgcn_mfma_f32_16x16x32_bf16(al, bh0, acc[tr][0], 0, 0, 0);
            acc[tr][0] = __builtin_amdgcn_mfma_f32_16x16x32_bf16(ah, bl0, acc[tr][0], 0, 0, 0);
            acc[tr][1] = __builtin_amdgcn_mfma_f32_16x16x32_bf16(ah, bh1, acc[tr][1], 0, 0, 0);
            acc[tr][1] = __builtin_amdgcn_mfma_f32_16x16x32_bf16(al, bh1, acc[tr][1], 0, 0, 0);
            acc[tr][1] = __builtin_amdgcn_mfma_f32_16x16x32_bf16(ah, bl1, acc[tr][1], 0, 0, 0);
        }
        __syncthreads();   // all frag reads done before next writes / Hbuf reuse
    }

    // ---- acc (C layout: row=16tr+4q+reg, col=16(2w+tc)+c16) -> mv layout
    //      h[e*32+j] = H[4l+e][32w+j]. Intra-wave LDS round trip (wave w's
    //      cols only; same-wave LDS ops are ordered, no barrier). ----
    const int qd4 = (l >> 4) * 4;
    const int c16 = l & 15;
    float* Hw = sm.Hbuf[w];
    float h[128];
#pragma unroll
    for (int rc = 0; rc < 8; ++rc) {           // rows 32rc..32rc+31
#pragma unroll
        for (int tt = 0; tt < 2; ++tt)
#pragma unroll
            for (int tc = 0; tc < 2; ++tc)
#pragma unroll
                for (int reg = 0; reg < 4; ++reg) {
                    int row_local = 16 * tt + qd4 + reg;
                    Hw[row_local * 36 + 16 * tc + c16] = acc[2 * rc + tt][tc][reg];
                }
        if ((l >> 3) == rc) {                   // lanes 8rc..8rc+7
            int l2 = l & 7;
#pragma unroll
            for (int e = 0; e < 4; ++e)
#pragma unroll
                for (int jj = 0; jj < 8; ++jj) {
                    float4 v = *(const float4*)&Hw[(4 * l2 + e) * 36 + 4 * jj];
                    h[e * 32 + jj * 4 + 0] = v.x;
                    h[e * 32 + jj * 4 + 1] = v.y;
                    h[e * 32 + jj * 4 + 2] = v.z;
                    h[e * 32 + jj * 4 + 3] = v.w;
                }
        }
    }

    // ================== power iteration ==================
    // lanes<16 hold the current y-slice (cols 32w+2l, +2l+1) in registers;
    // x is broadcast wave-wide via readlane each iteration (no LDS).
    float cy0 = 1.0f, cy1 = 1.0f;
    int phase = 0;
    for (int it = 0; it < PITERS; ++it, ++phase) {
        float xs[32];
#pragma unroll
        for (int j = 0; j < 16; ++j) {
            xs[2 * j]     = readlane_f(cy0, j);
            xs[2 * j + 1] = readlane_f(cy1, j);
        }
        mv_reg(h, xs, sm.red[phase & 1][w], l);
        __syncthreads();
        if (l < 16) {
            float2 s = gather_pair(sm.red[phase & 1], w, l);
            cy0 = s.x * 0.0009765625f;
            cy1 = s.y * 0.0009765625f;
        }
    }

    // ---- Rayleigh quotient -> step ----
    {
        float xs[32];
#pragma unroll
        for (int j = 0; j < 16; ++j) {
            xs[2 * j]     = readlane_f(cy0, j);
            xs[2 * j + 1] = readlane_f(cy1, j);
        }
        mv_reg(h, xs, sm.red[phase & 1][w], l);
    }
    __syncthreads();
    float n1 = 0.f, n2 = 0.f;
    if (l < 16) {
        float2 hv = gather_pair(sm.red[phase & 1], w, l);
        n1 = cy0 * hv.x + cy1 * hv.y;
        n2 = cy0 * cy0 + cy1 * cy1;
    }
#pragma unroll
    for (int off = 1; off < 64; off <<= 1) {
        n1 += __shfl_xor(n1, off);
        n2 += __shfl_xor(n2, off);
    }
    if (l == 0) { sm.scal[w] = n1; sm.scal[8 + w] = n2; }
    __syncthreads();
    float num = 0.f, den = 0.f;
#pragma unroll
    for (int ww = 0; ww < 8; ++ww) { num += sm.scal[ww]; den += sm.scal[8 + ww]; }
    float L = num / den;
    const float step = 1.0f / (1.05f * fmaxf(L, 1e-12f));
    ++phase;

    // ================== FISTA ==================
    float b0 = 0.f, b1 = 0.f, rr = 0.f;
    if (l < 16) {
        float2 q2 = *(const float2*)(q + b * NDIM + 32 * w + 2 * l);
        b0 = q2.x; b1 = q2.y;
        rr = mu[b * NCON + 16 * w + l] * ln_[b * NCON + 16 * w + l];
    }
    float li0 = 0.f, li1 = 0.f, tcur = 1.0f;
    cy0 = 0.0f; cy1 = 0.0f;                     // y0 = proj(0) = 0

    for (int it = 0; it < FITERS; ++it, ++phase) {
        float xs[32];
#pragma unroll
        for (int j = 0; j < 16; ++j) {
            xs[2 * j]     = readlane_f(cy0, j);
            xs[2 * j + 1] = readlane_f(cy1, j);
        }
        mv_reg(h, xs, sm.red[phase & 1][w], l);
        __syncthreads();
        float tn = 0.5f * (1.0f + sqrtf(1.0f + 4.0f * tcur * tcur));
        float ratio = (tcur - 1.0f) / tn;
        tcur = tn;
        if (l < 16) {
            float2 hy = gather_pair(sm.red[phase & 1], w, l);
            float z0 = cy0 - step * (hy.x + b0);
            float z1 = cy1 - step * (hy.y + b1);
            float nrm = sqrtf(z0 * z0 + z1 * z1);
            float scl = (nrm > rr) ? (rr / fmaxf(nrm, 1e-30f)) : 1.0f;
            float l0 = z0 * scl, l1 = z1 * scl;
            float yn0 = l0 + ratio * (l0 - li0);
            float yn1 = l1 + ratio * (l1 - li1);
            li0 = l0; li1 = l1;
            cy0 = yn0; cy1 = yn1;
        }
    }

    if (l < 16)
        *(float2*)(out + b * NDIM + 32 * w + 2 * l) = make_float2(li0, li1);
}

} // namespace

extern "C" void kernel_launch(void* const* d_in, const int* in_sizes, int n_in,
                              void* d_out, int out_size, void* d_ws, size_t ws_size,
                              hipStream_t stream) {
    const float* P   = (const float*)d_in[0];
    const float* q   = (const float*)d_in[1];
    const float* l_n = (const float*)d_in[2];
    const float* mu  = (const float*)d_in[3];
    float* out = (float*)d_out;
    qcqp_fista<<<dim3(512), dim3(512), 0, stream>>>(P, q, l_n, mu, out);
}